// Round 1
// baseline (17099.992 us; speedup 1.0000x reference)
//
#include <hip/hip_runtime.h>

// EncoderDecoder LSTM: B=512, T=512, I=128, H=512.
// enc LSTM (h0=c0=0) -> (hn,cn); dec LSTM over same x from (hn,cn); out = h_last @ fc_W^T + fc_b.
// Strategy R0: one kernel per timestep (1024 step kernels), bf16 MFMA 16x16x32,
// K=640 fuses x@Wih^T into the recurrent GEMM. Gates reordered n' = 4*hcol + gate
// so each WG owns full (i,f,g,o) quadruples and does the c/h update in-kernel.
// c stays fp32; h broadcast bf16 (double-buffered across steps).

typedef unsigned short u16;
typedef __bf16 bf16x8 __attribute__((ext_vector_type(8)));
typedef float f32x4 __attribute__((ext_vector_type(4)));
typedef int i32x4 __attribute__((ext_vector_type(4)));

#define B_SZ 512
#define H_DIM 512
#define I_DIM 128
#define K_TOT 640   // H + I
#define TILE 64
#define LDA 72      // padded LDS row stride (bf16 elems): +16B keeps b128 reads 2-way (free)

__device__ __forceinline__ u16 f2bf(float f) {
  unsigned u = __builtin_bit_cast(unsigned, f);
  u += 0x7fffu + ((u >> 16) & 1u);   // RNE
  return (u16)(u >> 16);
}
__device__ __forceinline__ float bf2f(u16 h) {
  unsigned u = ((unsigned)h) << 16;
  return __builtin_bit_cast(float, u);
}
__device__ __forceinline__ float sigm(float v) { return 1.0f / (1.0f + __expf(-v)); }
__device__ __forceinline__ float tanh_fast(float v) {
  float e = __expf(-2.0f * fabsf(v));
  float t = (1.0f - e) / (1.0f + e);
  return v < 0.0f ? -t : t;
}
__device__ __forceinline__ bf16x8 ld_frag(const u16* p) {
  i32x4 v = *reinterpret_cast<const i32x4*>(p);
  return __builtin_bit_cast(bf16x8, v);
}

// Build Wt[n'][k] bf16, n' in [0,2048), k in [0,640): k<512 -> Whh[j][k], else Wih[j][k-512],
// with j = (n'&3)*512 + (n'>>2)  (gate-major -> interleaved reorder).
__global__ void prep_w(const float* __restrict__ Whh, const float* __restrict__ Wih,
                       u16* __restrict__ Wt) {
  const int idx = blockIdx.x * 256 + threadIdx.x;       // 2048*640 total
  const int n = idx / K_TOT;
  const int k = idx - n * K_TOT;
  const int j = (n & 3) * 512 + (n >> 2);
  const float v = (k < H_DIM) ? Whh[(size_t)j * H_DIM + k]
                              : Wih[(size_t)j * I_DIM + (k - H_DIM)];
  Wt[idx] = f2bf(v);
}

__global__ void prep_bias(const float* __restrict__ bih, const float* __restrict__ bhh,
                          float* __restrict__ bias) {
  const int n = blockIdx.x * 256 + threadIdx.x;         // 2048 total
  const int j = (n & 3) * 512 + (n >> 2);
  bias[n] = bih[j] + bhh[j];
}

// One LSTM timestep: gates[b, n'] = [h_in | x_t] @ Wt^T(+bias), then c/h update.
// grid (32 gate-blocks, 8 batch-blocks), block 256 (4 waves). Each WG: 64x64 C tile.
__global__ __launch_bounds__(256)
void lstm_step(const u16* __restrict__ Wt, const float* __restrict__ bias,
               const float* __restrict__ x, int t,
               const u16* __restrict__ h_in, u16* __restrict__ h_out,
               float* __restrict__ c)
{
  __shared__ u16 As[TILE][LDA];          // [batch row][k]
  __shared__ u16 Bs[TILE][LDA];          // [n' row][k]  (Wt already n'-major, k-fast)
  __shared__ float gsc[4][16][TILE];     // per-wave gate scratch for C-layout shuffle

  const int tid  = threadIdx.x;
  const int lane = tid & 63;
  const int wv   = tid >> 6;
  const int n0   = blockIdx.x * TILE;    // g' column base
  const int b0   = blockIdx.y * TILE;    // batch row base

  f32x4 acc[4] = {};

  for (int kc = 0; kc < K_TOT / TILE; ++kc) {
    const int k0 = kc * TILE;
    // Stage A (h | x_t, bf16) and B (weights) : 2 x 16B per thread each.
#pragma unroll
    for (int i = 0; i < 2; ++i) {
      const int v   = tid + i * 256;
      const int row = v >> 3;
      const int kc8 = (v & 7) * 8;
      const int k   = k0 + kc8;
      *reinterpret_cast<i32x4*>(&Bs[row][kc8]) =
          *reinterpret_cast<const i32x4*>(&Wt[(size_t)(n0 + row) * K_TOT + k]);
      if (k < H_DIM) {
        *reinterpret_cast<i32x4*>(&As[row][kc8]) =
            *reinterpret_cast<const i32x4*>(&h_in[(size_t)(b0 + row) * H_DIM + k]);
      } else {
        const float* xs = &x[((size_t)(b0 + row) * 512 + t) * 128 + (k - H_DIM)];
        f32x4 x0 = *reinterpret_cast<const f32x4*>(xs);
        f32x4 x1 = *reinterpret_cast<const f32x4*>(xs + 4);
        i32x4 pk;
        pk[0] = (int)(f2bf(x0[0]) | ((unsigned)f2bf(x0[1]) << 16));
        pk[1] = (int)(f2bf(x0[2]) | ((unsigned)f2bf(x0[3]) << 16));
        pk[2] = (int)(f2bf(x1[0]) | ((unsigned)f2bf(x1[1]) << 16));
        pk[3] = (int)(f2bf(x1[2]) | ((unsigned)f2bf(x1[3]) << 16));
        *reinterpret_cast<i32x4*>(&As[row][kc8]) = pk;
      }
    }
    __syncthreads();
#pragma unroll
    for (int ks = 0; ks < 2; ++ks) {
      const int koff = ks * 32 + (lane >> 4) * 8;        // A/B operand: k = quad*8 + j
      bf16x8 af = ld_frag(&As[wv * 16 + (lane & 15)][koff]);
#pragma unroll
      for (int nt = 0; nt < 4; ++nt) {
        bf16x8 bf = ld_frag(&Bs[nt * 16 + (lane & 15)][koff]);
        acc[nt] = __builtin_amdgcn_mfma_f32_16x16x32_bf16(af, bf, acc[nt], 0, 0, 0);
      }
    }
    __syncthreads();
  }

  // Dump C tiles (C/D layout: col = lane&15, row = (lane>>4)*4 + reg) to per-wave LDS.
#pragma unroll
  for (int nt = 0; nt < 4; ++nt) {
    const int col = nt * 16 + (lane & 15);
    const int rb  = (lane >> 4) * 4;
#pragma unroll
    for (int i = 0; i < 4; ++i) gsc[wv][rb + i][col] = acc[nt][i];
  }
  // Within-wave LDS write->read: LDS pipe is in-order per wave; compiler inserts lgkmcnt.

  // Elementwise epilogue: each wave owns 16 batch rows x 16 h-cols (full i,f,g,o).
#pragma unroll
  for (int p = 0; p < 4; ++p) {
    const int idx = lane + p * 64;
    const int m   = idx >> 4;      // local batch row within wave strip
    const int hl  = idx & 15;      // local h-col
    f32x4 g4 = *reinterpret_cast<f32x4*>(&gsc[wv][m][hl * 4]);
    f32x4 b4 = *reinterpret_cast<const f32x4*>(&bias[n0 + hl * 4]);
    const float iv = sigm(g4[0] + b4[0]);
    const float fv = sigm(g4[1] + b4[1]);
    const float gv = tanh_fast(g4[2] + b4[2]);
    const float ov = sigm(g4[3] + b4[3]);
    const int bg = b0 + wv * 16 + m;
    const int hc = (n0 >> 2) + hl;
    const size_t ci = (size_t)bg * H_DIM + hc;
    const float cn = fv * c[ci] + iv * gv;
    c[ci] = cn;
    h_out[ci] = f2bf(ov * tanh_fast(cn));
  }
}

__global__ void fc_kernel(const u16* __restrict__ h, const float* __restrict__ fcW,
                          const float* __restrict__ fcb, float* __restrict__ out) {
  const int b = blockIdx.x;
  const int lane = threadIdx.x;   // 64
  float s = 0.0f;
#pragma unroll
  for (int j = 0; j < 8; ++j) {
    const int k = lane + j * 64;
    s += bf2f(h[(size_t)b * H_DIM + k]) * fcW[k];
  }
#pragma unroll
  for (int off = 32; off > 0; off >>= 1) s += __shfl_down(s, off);
  if (lane == 0) out[b] = s + fcb[0];
}

extern "C" void kernel_launch(void* const* d_in, const int* in_sizes, int n_in,
                              void* d_out, int out_size, void* d_ws, size_t ws_size,
                              hipStream_t stream) {
  const float* x       = (const float*)d_in[0];
  const float* enc_Wih = (const float*)d_in[1];
  const float* enc_Whh = (const float*)d_in[2];
  const float* enc_bih = (const float*)d_in[3];
  const float* enc_bhh = (const float*)d_in[4];
  const float* dec_Wih = (const float*)d_in[5];
  const float* dec_Whh = (const float*)d_in[6];
  const float* dec_bih = (const float*)d_in[7];
  const float* dec_bhh = (const float*)d_in[8];
  const float* fc_W    = (const float*)d_in[9];
  const float* fc_b    = (const float*)d_in[10];
  float* out = (float*)d_out;

  // ws carve (total ~7.4 MB)
  char* ws = (char*)d_ws;
  u16*   encWt   = (u16*)ws;                 ws += (size_t)2048 * K_TOT * 2;
  u16*   decWt   = (u16*)ws;                 ws += (size_t)2048 * K_TOT * 2;
  float* encBias = (float*)ws;               ws += 2048 * 4;
  float* decBias = (float*)ws;               ws += 2048 * 4;
  u16*   hbuf0   = (u16*)ws;                 ws += (size_t)B_SZ * H_DIM * 2;
  u16*   hbuf1   = (u16*)ws;                 ws += (size_t)B_SZ * H_DIM * 2;
  float* cbuf    = (float*)ws;               ws += (size_t)B_SZ * H_DIM * 4;

  // Prep: reorder/transpose/convert weights + combined biases (same work every call).
  prep_w<<<(2048 * K_TOT) / 256, 256, 0, stream>>>(enc_Whh, enc_Wih, encWt);
  prep_w<<<(2048 * K_TOT) / 256, 256, 0, stream>>>(dec_Whh, dec_Wih, decWt);
  prep_bias<<<2048 / 256, 256, 0, stream>>>(enc_bih, enc_bhh, encBias);
  prep_bias<<<2048 / 256, 256, 0, stream>>>(dec_bih, dec_bhh, decBias);

  // h0 = c0 = 0 (ws is re-poisoned before every call; must re-init).
  hipMemsetAsync(hbuf0, 0, (size_t)B_SZ * H_DIM * 2, stream);
  hipMemsetAsync(cbuf,  0, (size_t)B_SZ * H_DIM * 4, stream);

  u16* hb[2] = {hbuf0, hbuf1};
  dim3 grid(32, 8), blk(256);
  for (int s = 0; s < 1024; ++s) {
    const u16*   Wt = (s < 512) ? encWt   : decWt;
    const float* bs = (s < 512) ? encBias : decBias;
    const int t = s & 511;
    lstm_step<<<grid, blk, 0, stream>>>(Wt, bs, x, t, hb[s & 1], hb[(s + 1) & 1], cbuf);
  }
  // 1024 steps -> final decoder h is in hbuf0.
  fc_kernel<<<B_SZ, 64, 0, stream>>>(hbuf0, fc_W, fc_b, out);
}